// Round 6
// baseline (4100.418 us; speedup 1.0000x reference)
//
#include <hip/hip_runtime.h>
#include <stdint.h>

typedef __attribute__((ext_vector_type(8))) short short8;
typedef __attribute__((ext_vector_type(4))) float f32x4;
typedef __attribute__((ext_vector_type(4))) float float4v;
typedef __attribute__((ext_vector_type(4))) unsigned short ushort4v;

__device__ __forceinline__ float b2f(short u) {
  union { float f; uint32_t i; } v; v.i = ((uint32_t)(unsigned short)u) << 16; return v.f;
}
__device__ __forceinline__ short f2b(float f) {
  uint32_t x = __float_as_uint(f);
  uint32_t r = (x + 0x7fffu + ((x >> 16) & 1u)) >> 16;
  return (short)r;
}
__device__ __forceinline__ void gload16(const short* g, short* l) {
  __builtin_amdgcn_global_load_lds((__attribute__((address_space(1))) const void*)g,
                                   (__attribute__((address_space(3))) void*)l, 16, 0, 0);
}

// ---------------- fp32 -> bf16 convert ----------------
__global__ void f2b_kernel(const float* __restrict__ in, short* __restrict__ out, int n4) {
  int i = blockIdx.x * blockDim.x + threadIdx.x;
  int stride = gridDim.x * blockDim.x;
  for (; i < n4; i += stride) {
    float4v v = *((const float4v*)in + i);
    ushort4v o;
    o[0] = (unsigned short)f2b(v[0]); o[1] = (unsigned short)f2b(v[1]);
    o[2] = (unsigned short)f2b(v[2]); o[3] = (unsigned short)f2b(v[3]);
    *((ushort4v*)out + i) = o;
  }
}

// ---------------- build h0 ----------------
__global__ void h0_kernel(const float* __restrict__ label, const float* __restrict__ sq,
                          const float* __restrict__ onee, const float* __restrict__ zeroe,
                          short* __restrict__ h) {
  int i = blockIdx.x;
  const float* src = (i == 0) ? sq : (label[i - 1] > 0.5f ? onee : zeroe);
  int d = threadIdx.x * 4;
  float4v v = *(const float4v*)(src + d);
  ushort4v o;
  o[0] = (unsigned short)f2b(v[0]); o[1] = (unsigned short)f2b(v[1]);
  o[2] = (unsigned short)f2b(v[2]); o[3] = (unsigned short)f2b(v[3]);
#pragma unroll
  for (int b = 0; b < 8; ++b)
    *(ushort4v*)(h + ((size_t)b * 1024 + i) * 1024 + d) = o;
}

// ---------------- 256x256 GEMM (counted vmcnt) ----------------
__device__ __forceinline__ void stage_grp(const short* __restrict__ mat, size_t rc0,
                                          int K, int kt, short* dstbuf, int w, int lane, int g2) {
  const int w3 = w & 3;
  const int rlo = lane >> 3;
  const int us = (lane & 7) ^ rlo;
#pragma unroll
  for (int q = 0; q < 4; ++q) {
    int c;
    if (w < 4) c = g2 * 8 + w3 * 2 + (q & 1) + (q >> 1) * 16;
    else       c = g2 * 4 + w3 + (q & 1) * 8 + (q >> 1) * 16;
    int rih = (c & 15) * 8 + rlo;
    gload16(mat + (rc0 + (c >> 4) * 128 + rih) * (size_t)K + kt * 64 + us * 8,
            dstbuf + ((w >> 2) * 32 + c) * 512);
  }
}

template <int EPI>
__global__ __launch_bounds__(512, 2) void gemm256(const short* __restrict__ A,
                                                  const short* __restrict__ W,
                                                  const float* __restrict__ bias,
                                                  short* __restrict__ C,
                                                  int M, int N, int K) {
  __shared__ short lds[2 * 4 * 8192];
  const int tid = threadIdx.x, lane = tid & 63, w = tid >> 6;
  const int g = lane >> 4, l15 = lane & 15;
  const int wm = w >> 2, wn = w & 3;
  const int nbx = N >> 8;
  int nwg = gridDim.x, orig = blockIdx.x, cpx = nwg >> 3;
  int id = (orig & 7) * cpx + (orig >> 3);
  int bx = id % nbx, by = id / nbx;
  const size_t rowA = (size_t)by * 256, colB = (size_t)bx * 256;
  const int NT = K >> 6;

  const short* smat = (w < 4) ? A : W;
  const size_t src0 = (w < 4) ? rowA : colB;

  f32x4 acc[8][4];
#pragma unroll
  for (int i = 0; i < 8; ++i)
#pragma unroll
    for (int j = 0; j < 4; ++j) acc[i][j] = (f32x4){0.f, 0.f, 0.f, 0.f};

  int sxz0 = g ^ (l15 & 7);
  int sxz1 = (4 + g) ^ (l15 & 7);
  const short* abase = lds + wm * 8192 + l15 * 64;
  const short* bbase = lds + (2 + (wn >> 1)) * 8192 + ((wn & 1) * 64 + l15) * 64;

  stage_grp(smat, src0, K, 0, lds, w, lane, 0);
  stage_grp(smat, src0, K, 0, lds, w, lane, 1);
  asm volatile("s_waitcnt vmcnt(0)" ::: "memory");
  __builtin_amdgcn_s_barrier();

  int p = 0;
  for (int t = 0; t < NT; ++t) {
    const int po = p * 32768;
    short* nbuf = lds + (p ^ 1) * 32768;
    if (t + 1 < NT) stage_grp(smat, src0, K, t + 1, nbuf, w, lane, 0);
    short8 af[4][2], bf0[2][2], bf1[2][2];

#pragma unroll
    for (int i = 0; i < 4; ++i) {
      af[i][0] = *(const short8*)(abase + po + i * 1024 + sxz0 * 8);
      af[i][1] = *(const short8*)(abase + po + i * 1024 + sxz1 * 8);
    }
#pragma unroll
    for (int j = 0; j < 2; ++j) {
      bf0[j][0] = *(const short8*)(bbase + po + j * 1024 + sxz0 * 8);
      bf0[j][1] = *(const short8*)(bbase + po + j * 1024 + sxz1 * 8);
    }
    __builtin_amdgcn_s_barrier();
    __builtin_amdgcn_s_setprio(1);
#pragma unroll
    for (int i = 0; i < 4; ++i)
#pragma unroll
      for (int j = 0; j < 2; ++j)
#pragma unroll
        for (int ks = 0; ks < 2; ++ks)
          acc[i][j] = __builtin_amdgcn_mfma_f32_16x16x32_bf16(af[i][ks], bf0[j][ks], acc[i][j], 0, 0, 0);
    __builtin_amdgcn_s_setprio(0);
    if (t + 1 < NT) {
      asm volatile("s_waitcnt vmcnt(4)" ::: "memory");
      stage_grp(smat, src0, K, t + 1, nbuf, w, lane, 1);
    } else {
      asm volatile("s_waitcnt vmcnt(0)" ::: "memory");
    }
    __builtin_amdgcn_s_barrier();

#pragma unroll
    for (int j = 0; j < 2; ++j) {
      bf1[j][0] = *(const short8*)(bbase + po + (2 + j) * 1024 + sxz0 * 8);
      bf1[j][1] = *(const short8*)(bbase + po + (2 + j) * 1024 + sxz1 * 8);
    }
    __builtin_amdgcn_s_barrier();
    __builtin_amdgcn_s_setprio(1);
#pragma unroll
    for (int i = 0; i < 4; ++i)
#pragma unroll
      for (int j = 0; j < 2; ++j)
#pragma unroll
        for (int ks = 0; ks < 2; ++ks)
          acc[i][2 + j] = __builtin_amdgcn_mfma_f32_16x16x32_bf16(af[i][ks], bf1[j][ks], acc[i][2 + j], 0, 0, 0);
    __builtin_amdgcn_s_setprio(0);
    __builtin_amdgcn_s_barrier();

#pragma unroll
    for (int i = 0; i < 4; ++i) {
      af[i][0] = *(const short8*)(abase + po + (64 + i * 16) * 64 + sxz0 * 8);
      af[i][1] = *(const short8*)(abase + po + (64 + i * 16) * 64 + sxz1 * 8);
    }
    __builtin_amdgcn_s_barrier();
    __builtin_amdgcn_s_setprio(1);
#pragma unroll
    for (int i = 0; i < 4; ++i)
#pragma unroll
      for (int j = 0; j < 2; ++j)
#pragma unroll
        for (int ks = 0; ks < 2; ++ks)
          acc[4 + i][2 + j] = __builtin_amdgcn_mfma_f32_16x16x32_bf16(af[i][ks], bf1[j][ks], acc[4 + i][2 + j], 0, 0, 0);
    __builtin_amdgcn_s_setprio(0);
    __builtin_amdgcn_s_barrier();

    __builtin_amdgcn_s_setprio(1);
#pragma unroll
    for (int i = 0; i < 4; ++i)
#pragma unroll
      for (int j = 0; j < 2; ++j)
#pragma unroll
        for (int ks = 0; ks < 2; ++ks)
          acc[4 + i][j] = __builtin_amdgcn_mfma_f32_16x16x32_bf16(af[i][ks], bf0[j][ks], acc[4 + i][j], 0, 0, 0);
    __builtin_amdgcn_s_setprio(0);

    asm volatile("s_waitcnt vmcnt(4)" ::: "memory");
    __builtin_amdgcn_s_barrier();
    p ^= 1;
  }

  float bv[4];
#pragma unroll
  for (int j = 0; j < 4; ++j) bv[j] = bias[colB + wn * 64 + j * 16 + l15];
#pragma unroll
  for (int i = 0; i < 8; ++i) {
    size_t row = rowA + wm * 128 + i * 16 + g * 4;
#pragma unroll
    for (int j = 0; j < 4; ++j) {
      size_t col = colB + wn * 64 + j * 16 + l15;
#pragma unroll
      for (int r = 0; r < 4; ++r) {
        float v = acc[i][j][r] + bv[j];
        if (EPI == 1) v = fmaxf(v, 0.f);
        C[(row + r) * N + col] = f2b(v);
      }
    }
  }
}

// ---------------- 128x128 GEMM, 4 waves, 2 blocks/CU, counted vmcnt ----------------
// LDS per buffer: A [0..8191] rows 0-127, B [8192..16383] rows 0-127 (16384 shorts = 32KB).
// grp0 (6 loads/thread): all 16 A chunks + B ph1 chunks {0-3,8-11}; grp1 (2): B {4-7,12-15}.
__device__ __forceinline__ void stage128(const short* __restrict__ A, const short* __restrict__ W,
                                         size_t rowA, size_t colB, int K, int kt,
                                         short* dstbuf, int w, int lane, int grp) {
  const int rlo = lane >> 3;
  const int us = (lane & 7) ^ rlo;
  const int coff = kt * 64 + us * 8;
  if (grp == 0) {
#pragma unroll
    for (int q = 0; q < 4; ++q) {
      int c = w * 4 + q;
      gload16(A + (rowA + c * 8 + rlo) * (size_t)K + coff, dstbuf + c * 512 + lane * 8);
    }
#pragma unroll
    for (int e = 0; e < 2; ++e) {
      int i8 = w * 2 + e;
      int bc = (i8 & 3) + ((i8 >> 2) << 3);        // 0..3, 8..11
      gload16(W + (colB + bc * 8 + rlo) * (size_t)K + coff, dstbuf + 8192 + bc * 512 + lane * 8);
    }
  } else {
#pragma unroll
    for (int e = 0; e < 2; ++e) {
      int i8 = w * 2 + e;
      int bc = (i8 & 3) + 4 + ((i8 >> 2) << 3);    // 4..7, 12..15
      gload16(W + (colB + bc * 8 + rlo) * (size_t)K + coff, dstbuf + 8192 + bc * 512 + lane * 8);
    }
  }
}

template <int EPI>
__global__ __launch_bounds__(256, 2) void gemm128(const short* __restrict__ A,
                                                  const short* __restrict__ W,
                                                  const float* __restrict__ bias,
                                                  short* __restrict__ C,
                                                  int M, int N, int K) {
  __shared__ short lds[2 * 16384];  // 64 KiB
  const int tid = threadIdx.x, lane = tid & 63, w = tid >> 6;
  const int g = lane >> 4, l15 = lane & 15;
  const int wm = w >> 1, wn = w & 1;
  const int nbx = N >> 7;
  int nwg = gridDim.x, orig = blockIdx.x, cpx = nwg >> 3;
  int id = (orig & 7) * cpx + (orig >> 3);
  int bx = id % nbx, by = id / nbx;
  const size_t rowA = (size_t)by * 128, colB = (size_t)bx * 128;
  const int NT = K >> 6;

  f32x4 acc[4][4];
#pragma unroll
  for (int i = 0; i < 4; ++i)
#pragma unroll
    for (int j = 0; j < 4; ++j) acc[i][j] = (f32x4){0.f, 0.f, 0.f, 0.f};

  const int sxz0 = g ^ (l15 & 7), sxz1 = (4 + g) ^ (l15 & 7);

  stage128(A, W, rowA, colB, K, 0, lds, w, lane, 0);
  stage128(A, W, rowA, colB, K, 0, lds, w, lane, 1);
  asm volatile("s_waitcnt vmcnt(0)" ::: "memory");
  __builtin_amdgcn_s_barrier();

  int p = 0;
  for (int t = 0; t < NT; ++t) {
    short* nbuf = lds + (p ^ 1) * 16384;
    if (t + 1 < NT) stage128(A, W, rowA, colB, K, t + 1, nbuf, w, lane, 0);
    const int po = p * 16384;
    short8 af[4][2], bf[2][2];
#pragma unroll
    for (int i = 0; i < 4; ++i) {
      int ra = wm * 64 + i * 16 + l15;
      af[i][0] = *(const short8*)(lds + po + ra * 64 + sxz0 * 8);
      af[i][1] = *(const short8*)(lds + po + ra * 64 + sxz1 * 8);
    }
#pragma unroll
    for (int j = 0; j < 2; ++j) {
      int rb = wn * 64 + j * 16 + l15;
      bf[j][0] = *(const short8*)(lds + po + 8192 + rb * 64 + sxz0 * 8);
      bf[j][1] = *(const short8*)(lds + po + 8192 + rb * 64 + sxz1 * 8);
    }
    __builtin_amdgcn_s_setprio(1);
#pragma unroll
    for (int i = 0; i < 4; ++i)
#pragma unroll
      for (int j = 0; j < 2; ++j)
#pragma unroll
        for (int ks = 0; ks < 2; ++ks)
          acc[i][j] = __builtin_amdgcn_mfma_f32_16x16x32_bf16(af[i][ks], bf[j][ks], acc[i][j], 0, 0, 0);
    __builtin_amdgcn_s_setprio(0);
    if (t + 1 < NT) {
      asm volatile("s_waitcnt vmcnt(6)" ::: "memory");
      stage128(A, W, rowA, colB, K, t + 1, nbuf, w, lane, 1);
    } else {
      asm volatile("s_waitcnt vmcnt(0)" ::: "memory");
    }
    __builtin_amdgcn_s_barrier();
#pragma unroll
    for (int j = 0; j < 2; ++j) {
      int rb = wn * 64 + 32 + j * 16 + l15;
      bf[j][0] = *(const short8*)(lds + po + 8192 + rb * 64 + sxz0 * 8);
      bf[j][1] = *(const short8*)(lds + po + 8192 + rb * 64 + sxz1 * 8);
    }
    __builtin_amdgcn_s_setprio(1);
#pragma unroll
    for (int i = 0; i < 4; ++i)
#pragma unroll
      for (int j = 0; j < 2; ++j)
#pragma unroll
        for (int ks = 0; ks < 2; ++ks)
          acc[i][2 + j] = __builtin_amdgcn_mfma_f32_16x16x32_bf16(af[i][ks], bf[j][ks], acc[i][2 + j], 0, 0, 0);
    __builtin_amdgcn_s_setprio(0);
    asm volatile("s_waitcnt vmcnt(2)" ::: "memory");
    __builtin_amdgcn_s_barrier();
    p ^= 1;
  }

  float bv[4];
#pragma unroll
  for (int j = 0; j < 4; ++j) bv[j] = bias[colB + wn * 64 + j * 16 + l15];
#pragma unroll
  for (int i = 0; i < 4; ++i) {
    size_t row = rowA + wm * 64 + i * 16 + g * 4;
#pragma unroll
    for (int j = 0; j < 4; ++j) {
      size_t col = colB + wn * 64 + j * 16 + l15;
#pragma unroll
      for (int r = 0; r < 4; ++r) {
        float v = acc[i][j][r] + bv[j];
        if (EPI == 1) v = fmaxf(v, 0.f);
        C[(row + r) * N + col] = f2b(v);
      }
    }
  }
}

// ---------------- V transpose: V[b,k,(off+h*128+d)] -> Vt[bh][d][k] ----------------
__global__ __launch_bounds__(256) void tv_kernel(const short* __restrict__ src, int ld, int voff,
                                                 short* __restrict__ vt) {
  __shared__ short t[64 * 72];
  const int kt = blockIdx.x * 64, dt = blockIdx.y * 64, bh = blockIdx.z;
  const int b = bh >> 3, hh = bh & 7;
  const short* s = src + (size_t)(b * 1024 + kt) * ld + voff + hh * 128 + dt;
#pragma unroll
  for (int p = 0; p < 2; ++p) {
    int idx = p * 256 + threadIdx.x;
    int r = idx >> 3, u = idx & 7;
    *(short8*)&t[r * 72 + u * 8] = *(const short8*)&s[(size_t)r * ld + u * 8];
  }
  __syncthreads();
#pragma unroll
  for (int p = 0; p < 2; ++p) {
    int idx = p * 256 + threadIdx.x;
    int dd = idx >> 3, u = idx & 7;
    short8 o;
#pragma unroll
    for (int j = 0; j < 8; ++j) o[j] = t[(u * 8 + j) * 72 + dd];
    *(short8*)&vt[((size_t)bh * 128 + dt + dd) * 1024 + kt + u * 8] = o;
  }
}

// ---------------- flash attention: 64 q-rows/block, 3 blocks/CU, defer-rescale ----------------
template <bool CAUSAL>
__global__ __launch_bounds__(256, 3) void attn_kernel(const short* __restrict__ Qb, int ldq, int qoff,
                                                      const short* __restrict__ Kb, int ldk, int koff,
                                                      const short* __restrict__ Vt,
                                                      short* __restrict__ Ob) {
  __shared__ short k_lds[64 * 128];
  __shared__ short v_lds[128 * 64];
  __shared__ short p_lds[4 * 16 * 72];
  const int tid = threadIdx.x, lane = tid & 63, w = tid >> 6;
  const int g = lane >> 4, l15 = lane & 15;
  const int bh = blockIdx.y, b = bh >> 3, hh = bh & 7;
  int qi = blockIdx.x;
  if (CAUSAL) qi = (blockIdx.y & 32) ? 15 - qi : qi;
  const int q0 = qi * 64;
  const float scale = 0.08838834764831845f;
  const int ntiles = CAUSAL ? qi + 1 : 16;

  const int kr = w * 16 + (lane >> 4);
  const int vd = w * 32 + (lane >> 3);

  short8 qf[4];
  {
    int row = q0 + w * 16 + l15;
    const short* qp = Qb + (size_t)(b * 1024 + row) * ldq + qoff + hh * 128;
#pragma unroll
    for (int t = 0; t < 4; ++t) qf[t] = *(const short8*)(qp + t * 32 + g * 8);
  }

  f32x4 oacc[8];
  f32x4 lacc = (f32x4){0.f, 0.f, 0.f, 0.f};
  float m_st[4];
#pragma unroll
  for (int fo = 0; fo < 8; ++fo) oacc[fo] = (f32x4){0.f, 0.f, 0.f, 0.f};
#pragma unroll
  for (int r = 0; r < 4; ++r) m_st[r] = -3.0e38f;
  const short8 ones = {16256, 16256, 16256, 16256, 16256, 16256, 16256, 16256};

  // prologue: tile 0 -> LDS (direct), tile 1 -> regs
#pragma unroll
  for (int c = 0; c < 4; ++c) {
    int ch = w * 4 + c;
    int r = kr + c * 4;
    int us = (lane & 15) ^ (r & 7);
    gload16(Kb + (size_t)(b * 1024 + r) * ldk + koff + hh * 128 + us * 8, k_lds + ch * 512);
    int d = vd + c * 8;
    int usv = (lane & 7) ^ (d & 7);
    gload16(Vt + ((size_t)bh * 128 + d) * 1024 + usv * 8, v_lds + ch * 512);
  }
  __builtin_amdgcn_sched_barrier(0);
  short8 kreg[4], vreg[4];
  if (ntiles > 1) {
#pragma unroll
    for (int c = 0; c < 4; ++c) {
      int r = kr + c * 4;
      int us = (lane & 15) ^ (r & 7);
      kreg[c] = *(const short8*)(Kb + (size_t)(b * 1024 + 64 + r) * ldk + koff + hh * 128 + us * 8);
      int d = vd + c * 8;
      int usv = (lane & 7) ^ (d & 7);
      vreg[c] = *(const short8*)(Vt + ((size_t)bh * 128 + d) * 1024 + 64 + usv * 8);
    }
    asm volatile("s_waitcnt vmcnt(8)" ::: "memory");
  } else {
    asm volatile("s_waitcnt vmcnt(0)" ::: "memory");
  }
  __builtin_amdgcn_s_barrier();

  for (int kt = 0; kt < ntiles; ++kt) {
    // S = Q K^T
    f32x4 sacc[4];
#pragma unroll
    for (int fn = 0; fn < 4; ++fn) sacc[fn] = (f32x4){0.f, 0.f, 0.f, 0.f};
#pragma unroll
    for (int t = 0; t < 4; ++t) {
      short8 kf[4];
#pragma unroll
      for (int fn = 0; fn < 4; ++fn) {
        int rowk = fn * 16 + l15;
        int u = (4 * t + g) ^ (rowk & 7);
        kf[fn] = *(const short8*)((const char*)k_lds + rowk * 256 + u * 16);
      }
      __builtin_amdgcn_s_setprio(1);
#pragma unroll
      for (int fn = 0; fn < 4; ++fn)
        sacc[fn] = __builtin_amdgcn_mfma_f32_16x16x32_bf16(qf[t], kf[fn], sacc[fn], 0, 0, 0);
      __builtin_amdgcn_s_setprio(0);
    }

    // online softmax with defer-rescale (THR=8)
#pragma unroll
    for (int reg = 0; reg < 4; ++reg) {
      float sv[4];
      float mt = -3.0e38f;
#pragma unroll
      for (int fn = 0; fn < 4; ++fn) {
        float s = sacc[fn][reg] * scale;
        if (CAUSAL) {
          int kg = kt * 64 + fn * 16 + l15;
          int qg = q0 + w * 16 + g * 4 + reg;
          if (kg > qg) s = -1e30f;
        }
        sv[fn] = s;
        mt = fmaxf(mt, s);
      }
#pragma unroll
      for (int off = 1; off < 16; off <<= 1) mt = fmaxf(mt, __shfl_xor(mt, off));
      float mo = m_st[reg];
      if (__any(mt > mo + 8.f)) {
        float mn = fmaxf(mo, mt);
        float corr = __expf(mo - mn);
        lacc[reg] *= corr;
#pragma unroll
        for (int fo = 0; fo < 8; ++fo) oacc[fo][reg] *= corr;
        m_st[reg] = mn;
        mo = mn;
      }
#pragma unroll
      for (int fn = 0; fn < 4; ++fn) {
        float p = __expf(sv[fn] - mo);
        p_lds[w * 1152 + (g * 4 + reg) * 72 + fn * 16 + l15] = f2b(p);
      }
    }

    // O += P V ; l += P * 1   (p_lds region per-wave)
#pragma unroll
    for (int t = 0; t < 2; ++t) {
      short8 pf = *(const short8*)(p_lds + w * 1152 + l15 * 72 + t * 32 + g * 8);
      __builtin_amdgcn_s_setprio(1);
      lacc = __builtin_amdgcn_mfma_f32_16x16x32_bf16(pf, ones, lacc, 0, 0, 0);
      __builtin_amdgcn_s_setprio(0);
#pragma unroll
      for (int fo = 0; fo < 8; ++fo) {
        int rowd = fo * 16 + l15;
        int u = (4 * t + g) ^ (rowd & 7);
        short8 vf = *(const short8*)((const char*)v_lds + rowd * 128 + u * 16);
        __builtin_amdgcn_s_setprio(1);
        oacc[fo] = __builtin_amdgcn_mfma_f32_16x16x32_bf16(pf, vf, oacc[fo], 0, 0, 0);
        __builtin_amdgcn_s_setprio(0);
      }
    }

    // stage next tile: regs -> LDS, then issue loads for kt+2
    if (kt + 1 < ntiles) {
      __builtin_amdgcn_s_barrier();
      asm volatile("s_waitcnt vmcnt(0)" ::: "memory");
#pragma unroll
      for (int c = 0; c < 4; ++c) {
        int ch = w * 4 + c;
        *(short8*)(k_lds + ch * 512 + lane * 8) = kreg[c];
        *(short8*)(v_lds + ch * 512 + lane * 8) = vreg[c];
      }
      if (kt + 2 < ntiles) {
#pragma unroll
        for (int c = 0; c < 4; ++c) {
          int r = kr + c * 4;
          int us = (lane & 15) ^ (r & 7);
          kreg[c] = *(const short8*)(Kb + (size_t)(b * 1024 + (kt + 2) * 64 + r) * ldk + koff + hh * 128 + us * 8);
          int d = vd + c * 8;
          int usv = (lane & 7) ^ (d & 7);
          vreg[c] = *(const short8*)(Vt + ((size_t)bh * 128 + d) * 1024 + (kt + 2) * 64 + usv * 8);
        }
      }
      asm volatile("s_waitcnt lgkmcnt(0)" ::: "memory");
      __builtin_amdgcn_s_barrier();
    }
  }

  // epilogue
#pragma unroll
  for (int fo = 0; fo < 8; ++fo)
#pragma unroll
    for (int reg = 0; reg < 4; ++reg) {
      int row = q0 + w * 16 + g * 4 + reg;
      int col = hh * 128 + fo * 16 + l15;
      float o = oacc[fo][reg] / lacc[reg];
      Ob[(size_t)(b * 1024 + row) * 1024 + col] = f2b(o);
    }
}

// ---------------- fused residual + LayerNorm ----------------
__global__ __launch_bounds__(128) void ln_kernel(const short* __restrict__ h,
                                                 const short* __restrict__ delta,
                                                 const float* __restrict__ gg,
                                                 const float* __restrict__ bb,
                                                 short* __restrict__ out) {
  __shared__ float red[4];
  const int row = blockIdx.x, tid = threadIdx.x;
  const short8 hv = *(const short8*)(h + (size_t)row * 1024 + tid * 8);
  const short8 dv = *(const short8*)(delta + (size_t)row * 1024 + tid * 8);
  float x[8];
  float s = 0.f, s2 = 0.f;
#pragma unroll
  for (int j = 0; j < 8; ++j) {
    x[j] = b2f(hv[j]) + b2f(dv[j]);
    s += x[j];
    s2 += x[j] * x[j];
  }
#pragma unroll
  for (int o = 1; o < 64; o <<= 1) { s += __shfl_xor(s, o); s2 += __shfl_xor(s2, o); }
  if ((tid & 63) == 0) { red[(tid >> 6) * 2] = s; red[(tid >> 6) * 2 + 1] = s2; }
  __syncthreads();
  s = red[0] + red[2];
  s2 = red[1] + red[3];
  const float mu = s * (1.f / 1024.f);
  const float var = s2 * (1.f / 1024.f) - mu * mu;
  const float rs = rsqrtf(var + 1e-5f);
  short8 o;
#pragma unroll
  for (int j = 0; j < 8; ++j) {
    int d = tid * 8 + j;
    o[j] = f2b((x[j] - mu) * rs * gg[d] + bb[d]);
  }
  *(short8*)(out + (size_t)row * 1024 + tid * 8) = o;
}

// ---------------- classifier ----------------
__global__ __launch_bounds__(256) void cls_kernel(const short* __restrict__ h,
                                                  const float* __restrict__ wv,
                                                  const float* __restrict__ bias,
                                                  float* __restrict__ out) {
  const int lane = threadIdx.x & 63, w = threadIdx.x >> 6;
  const int row = blockIdx.x * 4 + w;
  const short* hp = h + (size_t)row * 1024 + lane * 16;
  float sum = 0.f;
#pragma unroll
  for (int i = 0; i < 2; ++i) {
    short8 v = *(const short8*)(hp + i * 8);
#pragma unroll
    for (int j = 0; j < 8; ++j) sum += b2f(v[j]) * wv[lane * 16 + i * 8 + j];
  }
#pragma unroll
  for (int o = 1; o < 64; o <<= 1) sum += __shfl_xor(sum, o);
  if (lane == 0) {
    float z = sum + bias[0];
    out[row] = 1.f / (1.f + __expf(-z));
  }
}

// ---------------- workspace layout (bf16 elems) ----------------
#define O_SA_IN  ((size_t)0)
#define O_SA_OUT ((size_t)18874368)
#define O_CA_IN  ((size_t)25165824)
#define O_CA_OUT ((size_t)44040192)
#define O_LIN1   ((size_t)50331648)
#define O_LIN2   ((size_t)62914560)
#define O_X      ((size_t)75497472)
#define O_H      ((size_t)83886080)
#define O_QKV    ((size_t)92274688)
#define O_ATTN   ((size_t)117440512)
#define O_DELTA  ((size_t)125829120)
#define O_VT     ((size_t)134217728)
#define O_FF1    ((size_t)142606336)

extern "C" void kernel_launch(void* const* d_in, const int* in_sizes, int n_in,
                              void* d_out, int out_size, void* d_ws, size_t ws_size,
                              hipStream_t stream) {
  const float* x = (const float*)d_in[0];
  const float* label = (const float*)d_in[1];
  const float* sq = (const float*)d_in[2];
  const float* onee = (const float*)d_in[3];
  const float* zeroe = (const float*)d_in[4];
  const float* sa_in_w = (const float*)d_in[5];
  const float* sa_in_b = (const float*)d_in[6];
  const float* sa_out_w = (const float*)d_in[7];
  const float* sa_out_b = (const float*)d_in[8];
  const float* ca_in_w = (const float*)d_in[9];
  const float* ca_in_b = (const float*)d_in[10];
  const float* ca_out_w = (const float*)d_in[11];
  const float* ca_out_b = (const float*)d_in[12];
  const float* lin1_w = (const float*)d_in[13];
  const float* lin1_b = (const float*)d_in[14];
  const float* lin2_w = (const float*)d_in[15];
  const float* lin2_b = (const float*)d_in[16];
  const float* ln_g = (const float*)d_in[17];
  const float* ln_b = (const float*)d_in[18];
  const float* cls_w = (const float*)d_in[19];
  const float* cls_b = (const float*)d_in[20];

  short* ws = (short*)d_ws;
  short* w_sa_in = ws + O_SA_IN;
  short* w_sa_out = ws + O_SA_OUT;
  short* w_ca_in = ws + O_CA_IN;
  short* w_ca_out = ws + O_CA_OUT;
  short* w_lin1 = ws + O_LIN1;
  short* w_lin2 = ws + O_LIN2;
  short* xb = ws + O_X;
  short* hbuf = ws + O_H;
  short* qkv = ws + O_QKV;
  short* kvb = qkv + 8388608;
  short* attnb = ws + O_ATTN;
  short* delta = ws + O_DELTA;
  short* vt = ws + O_VT;
  short* ff1 = ws + O_FF1;

  f2b_kernel<<<4096, 256, 0, stream>>>(sa_in_w, w_sa_in, 18874368 / 4);
  f2b_kernel<<<4096, 256, 0, stream>>>(sa_out_w, w_sa_out, 6291456 / 4);
  f2b_kernel<<<4096, 256, 0, stream>>>(ca_in_w, w_ca_in, 18874368 / 4);
  f2b_kernel<<<4096, 256, 0, stream>>>(ca_out_w, w_ca_out, 6291456 / 4);
  f2b_kernel<<<4096, 256, 0, stream>>>(lin1_w, w_lin1, 12582912 / 4);
  f2b_kernel<<<4096, 256, 0, stream>>>(lin2_w, w_lin2, 12582912 / 4);
  f2b_kernel<<<4096, 256, 0, stream>>>(x, xb, 8388608 / 4);
  h0_kernel<<<1024, 256, 0, stream>>>(label, sq, onee, zeroe, hbuf);

  for (int l = 0; l < 6; ++l) {
    // ---- self-attention ----
    gemm256<0><<<384, 512, 0, stream>>>(hbuf, w_sa_in + (size_t)l * 3145728,
                                        sa_in_b + (size_t)l * 3072, qkv, 8192, 3072, 1024);
    tv_kernel<<<dim3(16, 2, 64), 256, 0, stream>>>(qkv, 3072, 2048, vt);
    attn_kernel<true><<<dim3(16, 64), 256, 0, stream>>>(qkv, 3072, 0, qkv, 3072, 1024, vt, attnb);
    gemm128<0><<<512, 256, 0, stream>>>(attnb, w_sa_out + (size_t)l * 1048576,
                                        sa_out_b + (size_t)l * 1024, delta, 8192, 1024, 1024);
    ln_kernel<<<8192, 128, 0, stream>>>(hbuf, delta, ln_g + (size_t)(l * 3 + 0) * 1024,
                                        ln_b + (size_t)(l * 3 + 0) * 1024, hbuf);
    // ---- cross-attention ----
    gemm128<0><<<512, 256, 0, stream>>>(hbuf, w_ca_in + (size_t)l * 3145728,
                                        ca_in_b + (size_t)l * 3072, qkv, 8192, 1024, 1024);
    gemm256<0><<<256, 512, 0, stream>>>(xb, w_ca_in + (size_t)l * 3145728 + 1048576,
                                        ca_in_b + (size_t)l * 3072 + 1024, kvb, 8192, 2048, 1024);
    tv_kernel<<<dim3(16, 2, 64), 256, 0, stream>>>(kvb, 2048, 1024, vt);
    attn_kernel<false><<<dim3(16, 64), 256, 0, stream>>>(qkv, 1024, 0, kvb, 2048, 0, vt, attnb);
    gemm128<0><<<512, 256, 0, stream>>>(attnb, w_ca_out + (size_t)l * 1048576,
                                        ca_out_b + (size_t)l * 1024, delta, 8192, 1024, 1024);
    ln_kernel<<<8192, 128, 0, stream>>>(hbuf, delta, ln_g + (size_t)(l * 3 + 1) * 1024,
                                        ln_b + (size_t)(l * 3 + 1) * 1024, hbuf);
    // ---- feed-forward ----
    gemm256<1><<<256, 512, 0, stream>>>(hbuf, w_lin1 + (size_t)l * 2097152,
                                        lin1_b + (size_t)l * 2048, ff1, 8192, 2048, 1024);
    gemm128<0><<<512, 256, 0, stream>>>(ff1, w_lin2 + (size_t)l * 2097152,
                                        lin2_b + (size_t)l * 1024, delta, 8192, 1024, 2048);
    ln_kernel<<<8192, 128, 0, stream>>>(hbuf, delta, ln_g + (size_t)(l * 3 + 2) * 1024,
                                        ln_b + (size_t)(l * 3 + 2) * 1024, hbuf);
  }
  cls_kernel<<<2048, 256, 0, stream>>>(hbuf, cls_w, cls_b, (float*)d_out);
}

// Round 7
// 2569.977 us; speedup vs baseline: 1.5955x; 1.5955x over previous
//
#include <hip/hip_runtime.h>
#include <stdint.h>

typedef __attribute__((ext_vector_type(8))) short short8;
typedef __attribute__((ext_vector_type(4))) float f32x4;
typedef __attribute__((ext_vector_type(4))) float float4v;
typedef __attribute__((ext_vector_type(4))) unsigned short ushort4v;

__device__ __forceinline__ float b2f(short u) {
  union { float f; uint32_t i; } v; v.i = ((uint32_t)(unsigned short)u) << 16; return v.f;
}
__device__ __forceinline__ short f2b(float f) {
  uint32_t x = __float_as_uint(f);
  uint32_t r = (x + 0x7fffu + ((x >> 16) & 1u)) >> 16;
  return (short)r;
}
__device__ __forceinline__ void gload16(const short* g, short* l) {
  __builtin_amdgcn_global_load_lds((__attribute__((address_space(1))) const void*)g,
                                   (__attribute__((address_space(3))) void*)l, 16, 0, 0);
}

// ---------------- fp32 -> bf16 convert ----------------
__global__ void f2b_kernel(const float* __restrict__ in, short* __restrict__ out, int n4) {
  int i = blockIdx.x * blockDim.x + threadIdx.x;
  int stride = gridDim.x * blockDim.x;
  for (; i < n4; i += stride) {
    float4v v = *((const float4v*)in + i);
    ushort4v o;
    o[0] = (unsigned short)f2b(v[0]); o[1] = (unsigned short)f2b(v[1]);
    o[2] = (unsigned short)f2b(v[2]); o[3] = (unsigned short)f2b(v[3]);
    *((ushort4v*)out + i) = o;
  }
}

// ---------------- build h0 ----------------
__global__ void h0_kernel(const float* __restrict__ label, const float* __restrict__ sq,
                          const float* __restrict__ onee, const float* __restrict__ zeroe,
                          short* __restrict__ h) {
  int i = blockIdx.x;
  const float* src = (i == 0) ? sq : (label[i - 1] > 0.5f ? onee : zeroe);
  int d = threadIdx.x * 4;
  float4v v = *(const float4v*)(src + d);
  ushort4v o;
  o[0] = (unsigned short)f2b(v[0]); o[1] = (unsigned short)f2b(v[1]);
  o[2] = (unsigned short)f2b(v[2]); o[3] = (unsigned short)f2b(v[3]);
#pragma unroll
  for (int b = 0; b < 8; ++b)
    *(ushort4v*)(h + ((size_t)b * 1024 + i) * 1024 + d) = o;
}

// ---------------- 256x256 GEMM (counted vmcnt) ----------------
__device__ __forceinline__ void stage_grp(const short* __restrict__ mat, size_t rc0,
                                          int K, int kt, short* dstbuf, int w, int lane, int g2) {
  const int w3 = w & 3;
  const int rlo = lane >> 3;
  const int us = (lane & 7) ^ rlo;
#pragma unroll
  for (int q = 0; q < 4; ++q) {
    int c;
    if (w < 4) c = g2 * 8 + w3 * 2 + (q & 1) + (q >> 1) * 16;
    else       c = g2 * 4 + w3 + (q & 1) * 8 + (q >> 1) * 16;
    int rih = (c & 15) * 8 + rlo;
    gload16(mat + (rc0 + (c >> 4) * 128 + rih) * (size_t)K + kt * 64 + us * 8,
            dstbuf + ((w >> 2) * 32 + c) * 512);
  }
}

template <int EPI>
__global__ __launch_bounds__(512, 2) void gemm256(const short* __restrict__ A,
                                                  const short* __restrict__ W,
                                                  const float* __restrict__ bias,
                                                  short* __restrict__ C,
                                                  int M, int N, int K) {
  __shared__ short lds[2 * 4 * 8192];
  const int tid = threadIdx.x, lane = tid & 63, w = tid >> 6;
  const int g = lane >> 4, l15 = lane & 15;
  const int wm = w >> 2, wn = w & 3;
  const int nbx = N >> 8;
  int nwg = gridDim.x, orig = blockIdx.x, cpx = nwg >> 3;
  int id = (orig & 7) * cpx + (orig >> 3);
  int bx = id % nbx, by = id / nbx;
  const size_t rowA = (size_t)by * 256, colB = (size_t)bx * 256;
  const int NT = K >> 6;

  const short* smat = (w < 4) ? A : W;
  const size_t src0 = (w < 4) ? rowA : colB;

  f32x4 acc[8][4];
#pragma unroll
  for (int i = 0; i < 8; ++i)
#pragma unroll
    for (int j = 0; j < 4; ++j) acc[i][j] = (f32x4){0.f, 0.f, 0.f, 0.f};

  int sxz0 = g ^ (l15 & 7);
  int sxz1 = (4 + g) ^ (l15 & 7);
  const short* abase = lds + wm * 8192 + l15 * 64;
  const short* bbase = lds + (2 + (wn >> 1)) * 8192 + ((wn & 1) * 64 + l15) * 64;

  stage_grp(smat, src0, K, 0, lds, w, lane, 0);
  stage_grp(smat, src0, K, 0, lds, w, lane, 1);
  asm volatile("s_waitcnt vmcnt(0)" ::: "memory");
  __builtin_amdgcn_s_barrier();

  int p = 0;
  for (int t = 0; t < NT; ++t) {
    const int po = p * 32768;
    short* nbuf = lds + (p ^ 1) * 32768;
    if (t + 1 < NT) stage_grp(smat, src0, K, t + 1, nbuf, w, lane, 0);
    short8 af[4][2], bf0[2][2], bf1[2][2];

#pragma unroll
    for (int i = 0; i < 4; ++i) {
      af[i][0] = *(const short8*)(abase + po + i * 1024 + sxz0 * 8);
      af[i][1] = *(const short8*)(abase + po + i * 1024 + sxz1 * 8);
    }
#pragma unroll
    for (int j = 0; j < 2; ++j) {
      bf0[j][0] = *(const short8*)(bbase + po + j * 1024 + sxz0 * 8);
      bf0[j][1] = *(const short8*)(bbase + po + j * 1024 + sxz1 * 8);
    }
    __builtin_amdgcn_s_barrier();
    __builtin_amdgcn_s_setprio(1);
#pragma unroll
    for (int i = 0; i < 4; ++i)
#pragma unroll
      for (int j = 0; j < 2; ++j)
#pragma unroll
        for (int ks = 0; ks < 2; ++ks)
          acc[i][j] = __builtin_amdgcn_mfma_f32_16x16x32_bf16(af[i][ks], bf0[j][ks], acc[i][j], 0, 0, 0);
    __builtin_amdgcn_s_setprio(0);
    if (t + 1 < NT) {
      asm volatile("s_waitcnt vmcnt(4)" ::: "memory");
      stage_grp(smat, src0, K, t + 1, nbuf, w, lane, 1);
    } else {
      asm volatile("s_waitcnt vmcnt(0)" ::: "memory");
    }
    __builtin_amdgcn_s_barrier();

#pragma unroll
    for (int j = 0; j < 2; ++j) {
      bf1[j][0] = *(const short8*)(bbase + po + (2 + j) * 1024 + sxz0 * 8);
      bf1[j][1] = *(const short8*)(bbase + po + (2 + j) * 1024 + sxz1 * 8);
    }
    __builtin_amdgcn_s_barrier();
    __builtin_amdgcn_s_setprio(1);
#pragma unroll
    for (int i = 0; i < 4; ++i)
#pragma unroll
      for (int j = 0; j < 2; ++j)
#pragma unroll
        for (int ks = 0; ks < 2; ++ks)
          acc[i][2 + j] = __builtin_amdgcn_mfma_f32_16x16x32_bf16(af[i][ks], bf1[j][ks], acc[i][2 + j], 0, 0, 0);
    __builtin_amdgcn_s_setprio(0);
    __builtin_amdgcn_s_barrier();

#pragma unroll
    for (int i = 0; i < 4; ++i) {
      af[i][0] = *(const short8*)(abase + po + (64 + i * 16) * 64 + sxz0 * 8);
      af[i][1] = *(const short8*)(abase + po + (64 + i * 16) * 64 + sxz1 * 8);
    }
    __builtin_amdgcn_s_barrier();
    __builtin_amdgcn_s_setprio(1);
#pragma unroll
    for (int i = 0; i < 4; ++i)
#pragma unroll
      for (int j = 0; j < 2; ++j)
#pragma unroll
        for (int ks = 0; ks < 2; ++ks)
          acc[4 + i][2 + j] = __builtin_amdgcn_mfma_f32_16x16x32_bf16(af[i][ks], bf1[j][ks], acc[4 + i][2 + j], 0, 0, 0);
    __builtin_amdgcn_s_setprio(0);
    __builtin_amdgcn_s_barrier();

    __builtin_amdgcn_s_setprio(1);
#pragma unroll
    for (int i = 0; i < 4; ++i)
#pragma unroll
      for (int j = 0; j < 2; ++j)
#pragma unroll
        for (int ks = 0; ks < 2; ++ks)
          acc[4 + i][j] = __builtin_amdgcn_mfma_f32_16x16x32_bf16(af[i][ks], bf0[j][ks], acc[4 + i][j], 0, 0, 0);
    __builtin_amdgcn_s_setprio(0);

    asm volatile("s_waitcnt vmcnt(4)" ::: "memory");
    __builtin_amdgcn_s_barrier();
    p ^= 1;
  }

  float bv[4];
#pragma unroll
  for (int j = 0; j < 4; ++j) bv[j] = bias[colB + wn * 64 + j * 16 + l15];
#pragma unroll
  for (int i = 0; i < 8; ++i) {
    size_t row = rowA + wm * 128 + i * 16 + g * 4;
#pragma unroll
    for (int j = 0; j < 4; ++j) {
      size_t col = colB + wn * 64 + j * 16 + l15;
#pragma unroll
      for (int r = 0; r < 4; ++r) {
        float v = acc[i][j][r] + bv[j];
        if (EPI == 1) v = fmaxf(v, 0.f);
        C[(row + r) * N + col] = f2b(v);
      }
    }
  }
}

// ---------------- 128x128 GEMM, 4 waves, counted vmcnt ----------------
__device__ __forceinline__ void stage128(const short* __restrict__ A, const short* __restrict__ W,
                                         size_t rowA, size_t colB, int K, int kt,
                                         short* dstbuf, int w, int lane, int grp) {
  const int rlo = lane >> 3;
  const int us = (lane & 7) ^ rlo;
  const int coff = kt * 64 + us * 8;
  if (grp == 0) {
#pragma unroll
    for (int q = 0; q < 4; ++q) {
      int c = w * 4 + q;
      gload16(A + (rowA + c * 8 + rlo) * (size_t)K + coff, dstbuf + c * 512 + lane * 8);
    }
#pragma unroll
    for (int e = 0; e < 2; ++e) {
      int i8 = w * 2 + e;
      int bc = (i8 & 3) + ((i8 >> 2) << 3);        // 0..3, 8..11
      gload16(W + (colB + bc * 8 + rlo) * (size_t)K + coff, dstbuf + 8192 + bc * 512 + lane * 8);
    }
  } else {
#pragma unroll
    for (int e = 0; e < 2; ++e) {
      int i8 = w * 2 + e;
      int bc = (i8 & 3) + 4 + ((i8 >> 2) << 3);    // 4..7, 12..15
      gload16(W + (colB + bc * 8 + rlo) * (size_t)K + coff, dstbuf + 8192 + bc * 512 + lane * 8);
    }
  }
}

template <int EPI>
__global__ __launch_bounds__(256, 2) void gemm128(const short* __restrict__ A,
                                                  const short* __restrict__ W,
                                                  const float* __restrict__ bias,
                                                  short* __restrict__ C,
                                                  int M, int N, int K) {
  __shared__ short lds[2 * 16384];  // 64 KiB
  const int tid = threadIdx.x, lane = tid & 63, w = tid >> 6;
  const int g = lane >> 4, l15 = lane & 15;
  const int wm = w >> 1, wn = w & 1;
  const int nbx = N >> 7;
  int nwg = gridDim.x, orig = blockIdx.x, cpx = nwg >> 3;
  int id = (orig & 7) * cpx + (orig >> 3);
  int bx = id % nbx, by = id / nbx;
  const size_t rowA = (size_t)by * 128, colB = (size_t)bx * 128;
  const int NT = K >> 6;

  f32x4 acc[4][4];
#pragma unroll
  for (int i = 0; i < 4; ++i)
#pragma unroll
    for (int j = 0; j < 4; ++j) acc[i][j] = (f32x4){0.f, 0.f, 0.f, 0.f};

  const int sxz0 = g ^ (l15 & 7), sxz1 = (4 + g) ^ (l15 & 7);

  stage128(A, W, rowA, colB, K, 0, lds, w, lane, 0);
  stage128(A, W, rowA, colB, K, 0, lds, w, lane, 1);
  asm volatile("s_waitcnt vmcnt(0)" ::: "memory");
  __builtin_amdgcn_s_barrier();

  int p = 0;
  for (int t = 0; t < NT; ++t) {
    short* nbuf = lds + (p ^ 1) * 16384;
    if (t + 1 < NT) stage128(A, W, rowA, colB, K, t + 1, nbuf, w, lane, 0);
    const int po = p * 16384;
    short8 af[4][2], bf[2][2];
#pragma unroll
    for (int i = 0; i < 4; ++i) {
      int ra = wm * 64 + i * 16 + l15;
      af[i][0] = *(const short8*)(lds + po + ra * 64 + sxz0 * 8);
      af[i][1] = *(const short8*)(lds + po + ra * 64 + sxz1 * 8);
    }
#pragma unroll
    for (int j = 0; j < 2; ++j) {
      int rb = wn * 64 + j * 16 + l15;
      bf[j][0] = *(const short8*)(lds + po + 8192 + rb * 64 + sxz0 * 8);
      bf[j][1] = *(const short8*)(lds + po + 8192 + rb * 64 + sxz1 * 8);
    }
    __builtin_amdgcn_s_setprio(1);
#pragma unroll
    for (int i = 0; i < 4; ++i)
#pragma unroll
      for (int j = 0; j < 2; ++j)
#pragma unroll
        for (int ks = 0; ks < 2; ++ks)
          acc[i][j] = __builtin_amdgcn_mfma_f32_16x16x32_bf16(af[i][ks], bf[j][ks], acc[i][j], 0, 0, 0);
    __builtin_amdgcn_s_setprio(0);
    if (t + 1 < NT) {
      asm volatile("s_waitcnt vmcnt(6)" ::: "memory");
      stage128(A, W, rowA, colB, K, t + 1, nbuf, w, lane, 1);
    } else {
      asm volatile("s_waitcnt vmcnt(0)" ::: "memory");
    }
    __builtin_amdgcn_s_barrier();
#pragma unroll
    for (int j = 0; j < 2; ++j) {
      int rb = wn * 64 + 32 + j * 16 + l15;
      bf[j][0] = *(const short8*)(lds + po + 8192 + rb * 64 + sxz0 * 8);
      bf[j][1] = *(const short8*)(lds + po + 8192 + rb * 64 + sxz1 * 8);
    }
    __builtin_amdgcn_s_setprio(1);
#pragma unroll
    for (int i = 0; i < 4; ++i)
#pragma unroll
      for (int j = 0; j < 2; ++j)
#pragma unroll
        for (int ks = 0; ks < 2; ++ks)
          acc[i][2 + j] = __builtin_amdgcn_mfma_f32_16x16x32_bf16(af[i][ks], bf[j][ks], acc[i][2 + j], 0, 0, 0);
    __builtin_amdgcn_s_setprio(0);
    asm volatile("s_waitcnt vmcnt(2)" ::: "memory");
    __builtin_amdgcn_s_barrier();
    p ^= 1;
  }

  float bv[4];
#pragma unroll
  for (int j = 0; j < 4; ++j) bv[j] = bias[colB + wn * 64 + j * 16 + l15];
#pragma unroll
  for (int i = 0; i < 4; ++i) {
    size_t row = rowA + wm * 64 + i * 16 + g * 4;
#pragma unroll
    for (int j = 0; j < 4; ++j) {
      size_t col = colB + wn * 64 + j * 16 + l15;
#pragma unroll
      for (int r = 0; r < 4; ++r) {
        float v = acc[i][j][r] + bv[j];
        if (EPI == 1) v = fmaxf(v, 0.f);
        C[(row + r) * N + col] = f2b(v);
      }
    }
  }
}

// ---------------- V transpose: V[b,k,(off+h*128+d)] -> Vt[bh][d][k] ----------------
__global__ __launch_bounds__(256) void tv_kernel(const short* __restrict__ src, int ld, int voff,
                                                 short* __restrict__ vt) {
  __shared__ short t[64 * 72];
  const int kt = blockIdx.x * 64, dt = blockIdx.y * 64, bh = blockIdx.z;
  const int b = bh >> 3, hh = bh & 7;
  const short* s = src + (size_t)(b * 1024 + kt) * ld + voff + hh * 128 + dt;
#pragma unroll
  for (int p = 0; p < 2; ++p) {
    int idx = p * 256 + threadIdx.x;
    int r = idx >> 3, u = idx & 7;
    *(short8*)&t[r * 72 + u * 8] = *(const short8*)&s[(size_t)r * ld + u * 8];
  }
  __syncthreads();
#pragma unroll
  for (int p = 0; p < 2; ++p) {
    int idx = p * 256 + threadIdx.x;
    int dd = idx >> 3, u = idx & 7;
    short8 o;
#pragma unroll
    for (int j = 0; j < 8; ++j) o[j] = t[(u * 8 + j) * 72 + dd];
    *(short8*)&vt[((size_t)bh * 128 + dt + dd) * 1024 + kt + u * 8] = o;
  }
}

// ---------------- flash attention (R5 structure; grid x=bh for XCD locality) ----------------
// grid = (64, nq): x = b*8+h (same-bh blocks share an XCD's L2 copy of K/V),
// y = q-tile. Causal balance: co-resident ids differ by 256 -> qi and qi+4, constant sum.
template <bool CAUSAL>
__global__ __launch_bounds__(256, 2) void attn_kernel(const short* __restrict__ Qb, int ldq, int qoff,
                                                      const short* __restrict__ Kb, int ldk, int koff,
                                                      const short* __restrict__ Vt,
                                                      short* __restrict__ Ob) {
  __shared__ short k_lds[64 * 128];
  __shared__ short v_lds[128 * 64];
  __shared__ short p_lds[4 * 32 * 72];
  const int tid = threadIdx.x, lane = tid & 63, w = tid >> 6;
  const int g = lane >> 4, l15 = lane & 15;
  const int bh = blockIdx.x, b = bh >> 3, hh = bh & 7;
  const int qi = blockIdx.y;
  const int q0 = qi * 128;
  const float scale = 0.08838834764831845f;
  const int ntiles = CAUSAL ? (q0 >> 6) + 2 : 16;

  const int kr = w * 16 + (lane >> 4);
  const int vd = w * 32 + (lane >> 3);

  short8 qf[2][4];
#pragma unroll
  for (int fm = 0; fm < 2; ++fm) {
    int row = q0 + w * 32 + fm * 16 + l15;
    const short* qp = Qb + (size_t)(b * 1024 + row) * ldq + qoff + hh * 128;
#pragma unroll
    for (int t = 0; t < 4; ++t) qf[fm][t] = *(const short8*)(qp + t * 32 + g * 8);
  }

  f32x4 oacc[2][8];
  f32x4 lacc[2];
  float m_st[2][4];
#pragma unroll
  for (int fm = 0; fm < 2; ++fm) {
#pragma unroll
    for (int fo = 0; fo < 8; ++fo) oacc[fm][fo] = (f32x4){0.f, 0.f, 0.f, 0.f};
    lacc[fm] = (f32x4){0.f, 0.f, 0.f, 0.f};
#pragma unroll
    for (int r = 0; r < 4; ++r) m_st[fm][r] = -3.0e38f;
  }
  const short8 ones = {16256, 16256, 16256, 16256, 16256, 16256, 16256, 16256};  // bf16 1.0

  // prologue: tile 0 -> LDS (direct), tile 1 -> regs
#pragma unroll
  for (int c = 0; c < 4; ++c) {
    int ch = w * 4 + c;
    int r = kr + c * 4;
    int us = (lane & 15) ^ (r & 7);
    gload16(Kb + (size_t)(b * 1024 + r) * ldk + koff + hh * 128 + us * 8, k_lds + ch * 512);
    int d = vd + c * 8;
    int usv = (lane & 7) ^ (d & 7);
    gload16(Vt + ((size_t)bh * 128 + d) * 1024 + usv * 8, v_lds + ch * 512);
  }
  __builtin_amdgcn_sched_barrier(0);
  short8 kreg[4], vreg[4];
  if (ntiles > 1) {
#pragma unroll
    for (int c = 0; c < 4; ++c) {
      int r = kr + c * 4;
      int us = (lane & 15) ^ (r & 7);
      kreg[c] = *(const short8*)(Kb + (size_t)(b * 1024 + 64 + r) * ldk + koff + hh * 128 + us * 8);
      int d = vd + c * 8;
      int usv = (lane & 7) ^ (d & 7);
      vreg[c] = *(const short8*)(Vt + ((size_t)bh * 128 + d) * 1024 + 64 + usv * 8);
    }
    asm volatile("s_waitcnt vmcnt(8)" ::: "memory");
  } else {
    asm volatile("s_waitcnt vmcnt(0)" ::: "memory");
  }
  __builtin_amdgcn_s_barrier();

  for (int kt = 0; kt < ntiles; ++kt) {
    // S = Q K^T
    f32x4 sacc[2][4];
#pragma unroll
    for (int fm = 0; fm < 2; ++fm)
#pragma unroll
      for (int fn = 0; fn < 4; ++fn) sacc[fm][fn] = (f32x4){0.f, 0.f, 0.f, 0.f};
#pragma unroll
    for (int t = 0; t < 4; ++t) {
      short8 kf[4];
#pragma unroll
      for (int fn = 0; fn < 4; ++fn) {
        int rowk = fn * 16 + l15;
        int u = (4 * t + g) ^ (rowk & 7);
        kf[fn] = *(const short8*)((const char*)k_lds + rowk * 256 + u * 16);
      }
      __builtin_amdgcn_s_setprio(1);
#pragma unroll
      for (int fm = 0; fm < 2; ++fm)
#pragma unroll
        for (int fn = 0; fn < 4; ++fn)
          sacc[fm][fn] = __builtin_amdgcn_mfma_f32_16x16x32_bf16(qf[fm][t], kf[fn], sacc[fm][fn], 0, 0, 0);
      __builtin_amdgcn_s_setprio(0);
    }

    // online softmax (sum via MFMA ones-column)
#pragma unroll
    for (int fm = 0; fm < 2; ++fm)
#pragma unroll
      for (int reg = 0; reg < 4; ++reg) {
        float sv[4];
        float mt = -3.0e38f;
#pragma unroll
        for (int fn = 0; fn < 4; ++fn) {
          float s = sacc[fm][fn][reg] * scale;
          if (CAUSAL) {
            int kg = kt * 64 + fn * 16 + l15;
            int qg = q0 + w * 32 + fm * 16 + g * 4 + reg;
            if (kg > qg) s = -1e30f;
          }
          sv[fn] = s;
          mt = fmaxf(mt, s);
        }
#pragma unroll
        for (int off = 1; off < 16; off <<= 1) mt = fmaxf(mt, __shfl_xor(mt, off));
        float mo = m_st[fm][reg];
        float mn = fmaxf(mo, mt);
        float corr = __expf(mo - mn);
#pragma unroll
        for (int fn = 0; fn < 4; ++fn) {
          float p = __expf(sv[fn] - mn);
          p_lds[w * 2304 + (fm * 16 + g * 4 + reg) * 72 + fn * 16 + l15] = f2b(p);
        }
        m_st[fm][reg] = mn;
        lacc[fm][reg] *= corr;
#pragma unroll
        for (int fo = 0; fo < 8; ++fo) oacc[fm][fo][reg] *= corr;
      }

    // O += P V ; l += P * 1   (p_lds region per-wave: no barrier needed)
#pragma unroll
    for (int t = 0; t < 2; ++t) {
      short8 pf[2];
#pragma unroll
      for (int fm = 0; fm < 2; ++fm)
        pf[fm] = *(const short8*)(p_lds + w * 2304 + (fm * 16 + l15) * 72 + t * 32 + g * 8);
      __builtin_amdgcn_s_setprio(1);
      lacc[0] = __builtin_amdgcn_mfma_f32_16x16x32_bf16(pf[0], ones, lacc[0], 0, 0, 0);
      lacc[1] = __builtin_amdgcn_mfma_f32_16x16x32_bf16(pf[1], ones, lacc[1], 0, 0, 0);
      __builtin_amdgcn_s_setprio(0);
#pragma unroll
      for (int fo = 0; fo < 8; ++fo) {
        int rowd = fo * 16 + l15;
        int u = (4 * t + g) ^ (rowd & 7);
        short8 vf = *(const short8*)((const char*)v_lds + rowd * 128 + u * 16);
        __builtin_amdgcn_s_setprio(1);
#pragma unroll
        for (int fm = 0; fm < 2; ++fm)
          oacc[fm][fo] = __builtin_amdgcn_mfma_f32_16x16x32_bf16(pf[fm], vf, oacc[fm][fo], 0, 0, 0);
        __builtin_amdgcn_s_setprio(0);
      }
    }

    // stage next tile: regs -> LDS, then issue loads for kt+2
    if (kt + 1 < ntiles) {
      __builtin_amdgcn_s_barrier();
      asm volatile("s_waitcnt vmcnt(0)" ::: "memory");
#pragma unroll
      for (int c = 0; c < 4; ++c) {
        int ch = w * 4 + c;
        *(short8*)(k_lds + ch * 512 + lane * 8) = kreg[c];
        *(short8*)(v_lds + ch * 512 + lane * 8) = vreg[c];
      }
      if (kt + 2 < ntiles) {
#pragma unroll
        for (int c = 0; c < 4; ++c) {
          int r = kr + c * 4;
          int us = (lane & 15) ^ (r & 7);
          kreg[c] = *(const short8*)(Kb + (size_t)(b * 1024 + (kt + 2) * 64 + r) * ldk + koff + hh * 128 + us * 8);
          int d = vd + c * 8;
          int usv = (lane & 7) ^ (d & 7);
          vreg[c] = *(const short8*)(Vt + ((size_t)bh * 128 + d) * 1024 + (kt + 2) * 64 + usv * 8);
        }
      }
      asm volatile("s_waitcnt lgkmcnt(0)" ::: "memory");
      __builtin_amdgcn_s_barrier();
    }
  }

  // epilogue
#pragma unroll
  for (int fm = 0; fm < 2; ++fm)
#pragma unroll
    for (int fo = 0; fo < 8; ++fo)
#pragma unroll
      for (int reg = 0; reg < 4; ++reg) {
        int row = q0 + w * 32 + fm * 16 + g * 4 + reg;
        int col = hh * 128 + fo * 16 + l15;
        float o = oacc[fm][fo][reg] / lacc[fm][reg];
        Ob[(size_t)(b * 1024 + row) * 1024 + col] = f2b(o);
      }
}

// ---------------- fused residual + LayerNorm ----------------
__global__ __launch_bounds__(128) void ln_kernel(const short* __restrict__ h,
                                                 const short* __restrict__ delta,
                                                 const float* __restrict__ gg,
                                                 const float* __restrict__ bb,
                                                 short* __restrict__ out) {
  __shared__ float red[4];
  const int row = blockIdx.x, tid = threadIdx.x;
  const short8 hv = *(const short8*)(h + (size_t)row * 1024 + tid * 8);
  const short8 dv = *(const short8*)(delta + (size_t)row * 1024 + tid * 8);
  float x[8];
  float s = 0.f, s2 = 0.f;
#pragma unroll
  for (int j = 0; j < 8; ++j) {
    x[j] = b2f(hv[j]) + b2f(dv[j]);
    s += x[j];
    s2 += x[j] * x[j];
  }
#pragma unroll
  for (int o = 1; o < 64; o <<= 1) { s += __shfl_xor(s, o); s2 += __shfl_xor(s2, o); }
  if ((tid & 63) == 0) { red[(tid >> 6) * 2] = s; red[(tid >> 6) * 2 + 1] = s2; }
  __syncthreads();
  s = red[0] + red[2];
  s2 = red[1] + red[3];
  const float mu = s * (1.f / 1024.f);
  const float var = s2 * (1.f / 1024.f) - mu * mu;
  const float rs = rsqrtf(var + 1e-5f);
  short8 o;
#pragma unroll
  for (int j = 0; j < 8; ++j) {
    int d = tid * 8 + j;
    o[j] = f2b((x[j] - mu) * rs * gg[d] + bb[d]);
  }
  *(short8*)(out + (size_t)row * 1024 + tid * 8) = o;
}

// ---------------- classifier ----------------
__global__ __launch_bounds__(256) void cls_kernel(const short* __restrict__ h,
                                                  const float* __restrict__ wv,
                                                  const float* __restrict__ bias,
                                                  float* __restrict__ out) {
  const int lane = threadIdx.x & 63, w = threadIdx.x >> 6;
  const int row = blockIdx.x * 4 + w;
  const short* hp = h + (size_t)row * 1024 + lane * 16;
  float sum = 0.f;
#pragma unroll
  for (int i = 0; i < 2; ++i) {
    short8 v = *(const short8*)(hp + i * 8);
#pragma unroll
    for (int j = 0; j < 8; ++j) sum += b2f(v[j]) * wv[lane * 16 + i * 8 + j];
  }
#pragma unroll
  for (int o = 1; o < 64; o <<= 1) sum += __shfl_xor(sum, o);
  if (lane == 0) {
    float z = sum + bias[0];
    out[row] = 1.f / (1.f + __expf(-z));
  }
}

// ---------------- workspace layout (bf16 elems) ----------------
#define O_SA_IN  ((size_t)0)
#define O_SA_OUT ((size_t)18874368)
#define O_CA_IN  ((size_t)25165824)
#define O_CA_OUT ((size_t)44040192)
#define O_LIN1   ((size_t)50331648)
#define O_LIN2   ((size_t)62914560)
#define O_X      ((size_t)75497472)
#define O_H      ((size_t)83886080)
#define O_QKV    ((size_t)92274688)
#define O_ATTN   ((size_t)117440512)
#define O_DELTA  ((size_t)125829120)
#define O_VT     ((size_t)134217728)
#define O_FF1    ((size_t)142606336)

extern "C" void kernel_launch(void* const* d_in, const int* in_sizes, int n_in,
                              void* d_out, int out_size, void* d_ws, size_t ws_size,
                              hipStream_t stream) {
  const float* x = (const float*)d_in[0];
  const float* label = (const float*)d_in[1];
  const float* sq = (const float*)d_in[2];
  const float* onee = (const float*)d_in[3];
  const float* zeroe = (const float*)d_in[4];
  const float* sa_in_w = (const float*)d_in[5];
  const float* sa_in_b = (const float*)d_in[6];
  const float* sa_out_w = (const float*)d_in[7];
  const float* sa_out_b = (const float*)d_in[8];
  const float* ca_in_w = (const float*)d_in[9];
  const float* ca_in_b = (const float*)d_in[10];
  const float* ca_out_w = (const float*)d_in[11];
  const float* ca_out_b = (const float*)d_in[12];
  const float* lin1_w = (const float*)d_in[13];
  const float* lin1_b = (const float*)d_in[14];
  const float* lin2_w = (const float*)d_in[15];
  const float* lin2_b = (const float*)d_in[16];
  const float* ln_g = (const float*)d_in[17];
  const float* ln_b = (const float*)d_in[18];
  const float* cls_w = (const float*)d_in[19];
  const float* cls_b = (const float*)d_in[20];

  short* ws = (short*)d_ws;
  short* w_sa_in = ws + O_SA_IN;
  short* w_sa_out = ws + O_SA_OUT;
  short* w_ca_in = ws + O_CA_IN;
  short* w_ca_out = ws + O_CA_OUT;
  short* w_lin1 = ws + O_LIN1;
  short* w_lin2 = ws + O_LIN2;
  short* xb = ws + O_X;
  short* hbuf = ws + O_H;
  short* qkv = ws + O_QKV;
  short* kvb = qkv + 8388608;
  short* attnb = ws + O_ATTN;
  short* delta = ws + O_DELTA;
  short* vt = ws + O_VT;
  short* ff1 = ws + O_FF1;

  f2b_kernel<<<4096, 256, 0, stream>>>(sa_in_w, w_sa_in, 18874368 / 4);
  f2b_kernel<<<4096, 256, 0, stream>>>(sa_out_w, w_sa_out, 6291456 / 4);
  f2b_kernel<<<4096, 256, 0, stream>>>(ca_in_w, w_ca_in, 18874368 / 4);
  f2b_kernel<<<4096, 256, 0, stream>>>(ca_out_w, w_ca_out, 6291456 / 4);
  f2b_kernel<<<4096, 256, 0, stream>>>(lin1_w, w_lin1, 12582912 / 4);
  f2b_kernel<<<4096, 256, 0, stream>>>(lin2_w, w_lin2, 12582912 / 4);
  f2b_kernel<<<4096, 256, 0, stream>>>(x, xb, 8388608 / 4);
  h0_kernel<<<1024, 256, 0, stream>>>(label, sq, onee, zeroe, hbuf);

  for (int l = 0; l < 6; ++l) {
    // ---- self-attention ----
    gemm256<0><<<384, 512, 0, stream>>>(hbuf, w_sa_in + (size_t)l * 3145728,
                                        sa_in_b + (size_t)l * 3072, qkv, 8192, 3072, 1024);
    tv_kernel<<<dim3(16, 2, 64), 256, 0, stream>>>(qkv, 3072, 2048, vt);
    attn_kernel<true><<<dim3(64, 8), 256, 0, stream>>>(qkv, 3072, 0, qkv, 3072, 1024, vt, attnb);
    gemm128<0><<<512, 256, 0, stream>>>(attnb, w_sa_out + (size_t)l * 1048576,
                                        sa_out_b + (size_t)l * 1024, delta, 8192, 1024, 1024);
    ln_kernel<<<8192, 128, 0, stream>>>(hbuf, delta, ln_g + (size_t)(l * 3 + 0) * 1024,
                                        ln_b + (size_t)(l * 3 + 0) * 1024, hbuf);
    // ---- cross-attention ----
    gemm128<0><<<512, 256, 0, stream>>>(hbuf, w_ca_in + (size_t)l * 3145728,
                                        ca_in_b + (size_t)l * 3072, qkv, 8192, 1024, 1024);
    gemm256<0><<<256, 512, 0, stream>>>(xb, w_ca_in + (size_t)l * 3145728 + 1048576,
                                        ca_in_b + (size_t)l * 3072 + 1024, kvb, 8192, 2048, 1024);
    tv_kernel<<<dim3(16, 2, 64), 256, 0, stream>>>(kvb, 2048, 1024, vt);
    attn_kernel<false><<<dim3(64, 8), 256, 0, stream>>>(qkv, 1024, 0, kvb, 2048, 0, vt, attnb);
    gemm128<0><<<512, 256, 0, stream>>>(attnb, w_ca_out + (size_t)l * 1048576,
                                        ca_out_b + (size_t)l * 1024, delta, 8192, 1024, 1024);
    ln_kernel<<<8192, 128, 0, stream>>>(hbuf, delta, ln_g + (size_t)(l * 3 + 1) * 1024,
                                        ln_b + (size_t)(l * 3 + 1) * 1024, hbuf);
    // ---- feed-forward ----
    gemm256<1><<<256, 512, 0, stream>>>(hbuf, w_lin1 + (size_t)l * 2097152,
                                        lin1_b + (size_t)l * 2048, ff1, 8192, 2048, 1024);
    gemm128<0><<<512, 256, 0, stream>>>(ff1, w_lin2 + (size_t)l * 2097152,
                                        lin2_b + (size_t)l * 1024, delta, 8192, 1024, 2048);
    ln_kernel<<<8192, 128, 0, stream>>>(hbuf, delta, ln_g + (size_t)(l * 3 + 2) * 1024,
                                        ln_b + (size_t)(l * 3 + 2) * 1024, hbuf);
  }
  cls_kernel<<<2048, 256, 0, stream>>>(hbuf, cls_w, cls_b, (float*)d_out);
}